// Round 4
// baseline (1152.142 us; speedup 1.0000x reference)
//
#include <hip/hip_runtime.h>
#include <math.h>

// Workspace layout (uint32 words):
//  [0] maxbits   [1] sel_bin   [2] rank_in_bin
//  [3] done1 (pass1 last-block counter)   [4] done2 (pass2)
//  [8 .. 8+4096)            global histogram over top 12 bits of |x| bits
//  [4104 .. 4104+2048)      per-block max bits
//  [6152 .. 6152+2048)      per-block candidate counts
//  [8200 .. 8200+2048*256)  per-block candidate segments (CAP=256 each)
#define WS_MAXBITS 0
#define WS_SELBIN  1
#define WS_RANK    2
#define WS_DONE1   3
#define WS_DONE2   4
#define WS_HIST    8
#define HIST_WORDS 4096
#define WS_BMAX    (WS_HIST + HIST_WORDS)          // 4104
#define WS_CNT     (WS_BMAX + NBLK)                // 6152
#define WS_CAND    (WS_CNT + NBLK)                 // 8200
#define NBLK       2048
#define CAP        256

// clang-native vector type: __builtin_nontemporal_store requires it
typedef float floatx4 __attribute__((ext_vector_type(4)));

__device__ __forceinline__ unsigned int agent_inc_acqrel(unsigned int* p) {
    return __hip_atomic_fetch_add(p, 1u, __ATOMIC_ACQ_REL, __HIP_MEMORY_SCOPE_AGENT);
}

extern "C" __global__ void __launch_bounds__(256)
k_pass1(const float* __restrict__ x, long n, unsigned int* __restrict__ ws, long k) {
    __shared__ unsigned int lhist[HIST_WORDS];
    __shared__ unsigned int wred[4];
    __shared__ unsigned int s_last;
    __shared__ unsigned long long partial[256];
    __shared__ unsigned int mred[256];
    for (int i = threadIdx.x; i < HIST_WORDS; i += 256) lhist[i] = 0;
    __syncthreads();

    long n4 = n >> 2;
    const float4* x4 = (const float4*)x;
    unsigned int mymax = 0;
    long stride = (long)gridDim.x * 256;
    long i = (long)blockIdx.x * 256 + threadIdx.x;
    // unroll-4: four independent 16B loads in flight
    for (; i + 3 * stride < n4; i += 4 * stride) {
        float4 v0 = x4[i];
        float4 v1 = x4[i + stride];
        float4 v2 = x4[i + 2 * stride];
        float4 v3 = x4[i + 3 * stride];
        unsigned int a[16];
        a[0]  = __float_as_uint(v0.x) & 0x7fffffffu;
        a[1]  = __float_as_uint(v0.y) & 0x7fffffffu;
        a[2]  = __float_as_uint(v0.z) & 0x7fffffffu;
        a[3]  = __float_as_uint(v0.w) & 0x7fffffffu;
        a[4]  = __float_as_uint(v1.x) & 0x7fffffffu;
        a[5]  = __float_as_uint(v1.y) & 0x7fffffffu;
        a[6]  = __float_as_uint(v1.z) & 0x7fffffffu;
        a[7]  = __float_as_uint(v1.w) & 0x7fffffffu;
        a[8]  = __float_as_uint(v2.x) & 0x7fffffffu;
        a[9]  = __float_as_uint(v2.y) & 0x7fffffffu;
        a[10] = __float_as_uint(v2.z) & 0x7fffffffu;
        a[11] = __float_as_uint(v2.w) & 0x7fffffffu;
        a[12] = __float_as_uint(v3.x) & 0x7fffffffu;
        a[13] = __float_as_uint(v3.y) & 0x7fffffffu;
        a[14] = __float_as_uint(v3.z) & 0x7fffffffu;
        a[15] = __float_as_uint(v3.w) & 0x7fffffffu;
        #pragma unroll
        for (int e = 0; e < 16; e++) {
            mymax = max(mymax, a[e]);
            atomicAdd(&lhist[a[e] >> 20], 1u);
        }
    }
    for (; i < n4; i += stride) {
        float4 v = x4[i];
        unsigned int a0 = __float_as_uint(v.x) & 0x7fffffffu;
        unsigned int a1 = __float_as_uint(v.y) & 0x7fffffffu;
        unsigned int a2 = __float_as_uint(v.z) & 0x7fffffffu;
        unsigned int a3 = __float_as_uint(v.w) & 0x7fffffffu;
        mymax = max(mymax, max(max(a0, a1), max(a2, a3)));
        atomicAdd(&lhist[a0 >> 20], 1u);
        atomicAdd(&lhist[a1 >> 20], 1u);
        atomicAdd(&lhist[a2 >> 20], 1u);
        atomicAdd(&lhist[a3 >> 20], 1u);
    }
    // scalar tail (n % 4)
    if (blockIdx.x == 0 && threadIdx.x < (int)(n & 3)) {
        unsigned int a = __float_as_uint(x[n4 * 4 + threadIdx.x]) & 0x7fffffffu;
        mymax = max(mymax, a);
        atomicAdd(&lhist[a >> 20], 1u);
    }

    // wave64 max reduce → block reduce → plain store
    for (int off = 32; off > 0; off >>= 1)
        mymax = max(mymax, __shfl_down(mymax, off, 64));
    int lane = threadIdx.x & 63, wid = threadIdx.x >> 6;
    if (lane == 0) wred[wid] = mymax;
    __syncthreads();
    if (threadIdx.x == 0) {
        ws[WS_BMAX + blockIdx.x] =
            max(max(wred[0], wred[1]), max(wred[2], wred[3]));
    }
    // flush LDS histogram, rotated start so concurrent blocks spread addresses
    unsigned int rot = (blockIdx.x * 1297u) & (HIST_WORDS - 1);
    for (int idx = threadIdx.x; idx < HIST_WORDS; idx += 256) {
        unsigned int bin = (idx + rot) & (HIST_WORDS - 1);
        unsigned int c = lhist[bin];
        if (c) atomicAdd(&ws[WS_HIST + bin], c);
    }

    // ---- last-block scan fusion ----
    __threadfence();                 // release our plain stores device-wide
    __syncthreads();                 // all waves' memory ops drained (vmcnt 0)
    if (threadIdx.x == 0)
        s_last = (agent_inc_acqrel(&ws[WS_DONE1]) == (unsigned int)(gridDim.x - 1));
    __syncthreads();
    if (!s_last) return;
    // acquire on the RMW invalidated our caches; plain loads see fresh data.
    unsigned int m = 0;
    for (int s2 = threadIdx.x; s2 < NBLK; s2 += 256) m = max(m, ws[WS_BMAX + s2]);
    mred[threadIdx.x] = m;
    const unsigned int* hist = ws + WS_HIST;
    int base = threadIdx.x * (HIST_WORDS / 256);  // 16 bins per thread
    unsigned long long s = 0;
    for (int t = 0; t < 16; t++) s += hist[base + t];
    partial[threadIdx.x] = s;
    __syncthreads();
    if (threadIdx.x == 0) {
        unsigned int mm = 0;
        for (int t = 0; t < 256; t++) mm = max(mm, mred[t]);
        ws[WS_MAXBITS] = mm;
        unsigned long long acc = 0, before = 0;
        long bin = -1;
        for (int t = 0; t < 256; t++) {
            unsigned long long ps = partial[t];
            if (bin < 0 && acc + ps > (unsigned long long)k) {
                unsigned long long a2 = acc;
                for (int q = 0; q < 16; q++) {
                    unsigned int c = hist[t * 16 + q];
                    if (a2 + c > (unsigned long long)k) { bin = t * 16 + q; before = a2; break; }
                    a2 += c;
                }
            }
            acc += ps;
        }
        ws[WS_SELBIN] = (unsigned int)bin;
        ws[WS_RANK]   = (unsigned int)((unsigned long long)k - before);
        // kernel boundary publishes these to pass 2
    }
}

extern "C" __global__ void __launch_bounds__(256)
k_pass2(const float* __restrict__ x, float* __restrict__ out, long n,
        unsigned int* __restrict__ ws) {
    __shared__ unsigned int lbuf[CAP];
    __shared__ unsigned int lcnt;
    __shared__ unsigned int s_last;
    __shared__ unsigned int hist[1024];
    __shared__ unsigned int s_b1, s_j2;
    if (threadIdx.x == 0) lcnt = 0;
    __syncthreads();

    float xmax = __uint_as_float(ws[WS_MAXBITS]);
    unsigned int selbin = ws[WS_SELBIN];
    float scale = 127.0f / xmax;
    float inv = 1.0f / scale;

    long n4 = n >> 2;
    const float4* x4 = (const float4*)x;
    floatx4* out4 = (floatx4*)out;
    long stride = (long)gridDim.x * 256;
    long i = (long)blockIdx.x * 256 + threadIdx.x;
    for (; i + 3 * stride < n4; i += 4 * stride) {
        float4 v0 = x4[i];
        float4 v1 = x4[i + stride];
        float4 v2 = x4[i + 2 * stride];
        float4 v3 = x4[i + 3 * stride];
        floatx4 r0, r1, r2, r3;
        r0.x = fminf(fmaxf(rintf(v0.x * scale), -127.0f), 127.0f) * inv;
        r0.y = fminf(fmaxf(rintf(v0.y * scale), -127.0f), 127.0f) * inv;
        r0.z = fminf(fmaxf(rintf(v0.z * scale), -127.0f), 127.0f) * inv;
        r0.w = fminf(fmaxf(rintf(v0.w * scale), -127.0f), 127.0f) * inv;
        r1.x = fminf(fmaxf(rintf(v1.x * scale), -127.0f), 127.0f) * inv;
        r1.y = fminf(fmaxf(rintf(v1.y * scale), -127.0f), 127.0f) * inv;
        r1.z = fminf(fmaxf(rintf(v1.z * scale), -127.0f), 127.0f) * inv;
        r1.w = fminf(fmaxf(rintf(v1.w * scale), -127.0f), 127.0f) * inv;
        r2.x = fminf(fmaxf(rintf(v2.x * scale), -127.0f), 127.0f) * inv;
        r2.y = fminf(fmaxf(rintf(v2.y * scale), -127.0f), 127.0f) * inv;
        r2.z = fminf(fmaxf(rintf(v2.z * scale), -127.0f), 127.0f) * inv;
        r2.w = fminf(fmaxf(rintf(v2.w * scale), -127.0f), 127.0f) * inv;
        r3.x = fminf(fmaxf(rintf(v3.x * scale), -127.0f), 127.0f) * inv;
        r3.y = fminf(fmaxf(rintf(v3.y * scale), -127.0f), 127.0f) * inv;
        r3.z = fminf(fmaxf(rintf(v3.z * scale), -127.0f), 127.0f) * inv;
        r3.w = fminf(fmaxf(rintf(v3.w * scale), -127.0f), 127.0f) * inv;
        __builtin_nontemporal_store(r0, &out4[i]);
        __builtin_nontemporal_store(r1, &out4[i + stride]);
        __builtin_nontemporal_store(r2, &out4[i + 2 * stride]);
        __builtin_nontemporal_store(r3, &out4[i + 3 * stride]);
        unsigned int a[16];
        a[0]  = __float_as_uint(v0.x) & 0x7fffffffu;
        a[1]  = __float_as_uint(v0.y) & 0x7fffffffu;
        a[2]  = __float_as_uint(v0.z) & 0x7fffffffu;
        a[3]  = __float_as_uint(v0.w) & 0x7fffffffu;
        a[4]  = __float_as_uint(v1.x) & 0x7fffffffu;
        a[5]  = __float_as_uint(v1.y) & 0x7fffffffu;
        a[6]  = __float_as_uint(v1.z) & 0x7fffffffu;
        a[7]  = __float_as_uint(v1.w) & 0x7fffffffu;
        a[8]  = __float_as_uint(v2.x) & 0x7fffffffu;
        a[9]  = __float_as_uint(v2.y) & 0x7fffffffu;
        a[10] = __float_as_uint(v2.z) & 0x7fffffffu;
        a[11] = __float_as_uint(v2.w) & 0x7fffffffu;
        a[12] = __float_as_uint(v3.x) & 0x7fffffffu;
        a[13] = __float_as_uint(v3.y) & 0x7fffffffu;
        a[14] = __float_as_uint(v3.z) & 0x7fffffffu;
        a[15] = __float_as_uint(v3.w) & 0x7fffffffu;
        #pragma unroll
        for (int e = 0; e < 16; e++) {
            if ((a[e] >> 20) == selbin) {
                unsigned int p = atomicAdd(&lcnt, 1u);
                if (p < CAP) lbuf[p] = a[e];
            }
        }
    }
    for (; i < n4; i += stride) {
        float4 v = x4[i];
        floatx4 r;
        r.x = fminf(fmaxf(rintf(v.x * scale), -127.0f), 127.0f) * inv;
        r.y = fminf(fmaxf(rintf(v.y * scale), -127.0f), 127.0f) * inv;
        r.z = fminf(fmaxf(rintf(v.z * scale), -127.0f), 127.0f) * inv;
        r.w = fminf(fmaxf(rintf(v.w * scale), -127.0f), 127.0f) * inv;
        __builtin_nontemporal_store(r, &out4[i]);
        unsigned int a0 = __float_as_uint(v.x) & 0x7fffffffu;
        unsigned int a1 = __float_as_uint(v.y) & 0x7fffffffu;
        unsigned int a2 = __float_as_uint(v.z) & 0x7fffffffu;
        unsigned int a3 = __float_as_uint(v.w) & 0x7fffffffu;
        if ((a0 >> 20) == selbin) { unsigned int p = atomicAdd(&lcnt, 1u); if (p < CAP) lbuf[p] = a0; }
        if ((a1 >> 20) == selbin) { unsigned int p = atomicAdd(&lcnt, 1u); if (p < CAP) lbuf[p] = a1; }
        if ((a2 >> 20) == selbin) { unsigned int p = atomicAdd(&lcnt, 1u); if (p < CAP) lbuf[p] = a2; }
        if ((a3 >> 20) == selbin) { unsigned int p = atomicAdd(&lcnt, 1u); if (p < CAP) lbuf[p] = a3; }
    }
    // scalar tail
    if (blockIdx.x == 0 && threadIdx.x < (int)(n & 3)) {
        long t = n4 * 4 + threadIdx.x;
        float v = x[t];
        out[t] = fminf(fmaxf(rintf(v * scale), -127.0f), 127.0f) * inv;
        unsigned int a = __float_as_uint(v) & 0x7fffffffu;
        if ((a >> 20) == selbin) { unsigned int p = atomicAdd(&lcnt, 1u); if (p < CAP) lbuf[p] = a; }
    }
    __syncthreads();
    unsigned int c = lcnt; if (c > CAP) c = CAP;
    unsigned int* seg = ws + WS_CAND + (unsigned int)blockIdx.x * CAP;
    for (unsigned int e = threadIdx.x; e < c; e += 256) seg[e] = lbuf[e];
    if (threadIdx.x == 0) ws[WS_CNT + blockIdx.x] = c;

    // ---- last-block select fusion ----
    __threadfence();
    __syncthreads();
    if (threadIdx.x == 0)
        s_last = (agent_inc_acqrel(&ws[WS_DONE2]) == (unsigned int)(gridDim.x - 1));
    __syncthreads();
    if (!s_last) return;

    unsigned int j = ws[WS_RANK];
    for (int q = threadIdx.x; q < 1024; q += 256) hist[q] = 0;
    __syncthreads();
    for (int s2 = threadIdx.x; s2 < NBLK; s2 += 256) {
        unsigned int cc = ws[WS_CNT + s2]; if (cc > CAP) cc = CAP;
        const unsigned int* sg = ws + WS_CAND + (unsigned int)s2 * CAP;
        for (unsigned int e = 0; e < cc; e++)
            atomicAdd(&hist[(sg[e] >> 10) & 1023], 1u);
    }
    __syncthreads();
    if (threadIdx.x == 0) {
        unsigned int acc = 0, b1 = 1023;
        for (int b = 0; b < 1024; b++) {
            unsigned int h = hist[b];
            if (acc + h > j) { b1 = (unsigned int)b; break; }
            acc += h;
        }
        s_b1 = b1; s_j2 = j - acc;
    }
    __syncthreads();
    unsigned int pref = (selbin << 10) | s_b1;
    unsigned int j2 = s_j2;
    for (int q = threadIdx.x; q < 1024; q += 256) hist[q] = 0;
    __syncthreads();
    for (int s2 = threadIdx.x; s2 < NBLK; s2 += 256) {
        unsigned int cc = ws[WS_CNT + s2]; if (cc > CAP) cc = CAP;
        const unsigned int* sg = ws + WS_CAND + (unsigned int)s2 * CAP;
        for (unsigned int e = 0; e < cc; e++) {
            unsigned int u = sg[e];
            if ((u >> 10) == pref) atomicAdd(&hist[u & 1023], 1u);
        }
    }
    __syncthreads();
    if (threadIdx.x == 0) {
        unsigned int acc = 0, b2 = 1023;
        for (int b = 0; b < 1024; b++) {
            unsigned int h = hist[b];
            if (acc + h > j2) { b2 = (unsigned int)b; break; }
            acc += h;
        }
        float clampv = __uint_as_float((pref << 10) | b2);
        out[n] = (float)(100.0 * 0.99 + (double)clampv * 0.01);
    }
}

extern "C" void kernel_launch(void* const* d_in, const int* in_sizes, int n_in,
                              void* d_out, int out_size, void* d_ws, size_t ws_size,
                              hipStream_t stream) {
    const float* x = (const float*)d_in[0];
    long n = (long)in_sizes[0];
    float* out = (float*)d_out;
    unsigned int* ws = (unsigned int*)d_ws;

    // k = round(0.9999 * n) - 1, same double arithmetic as Python
    long k = (long)llround((99.99 / 100.0) * (double)n) - 1;
    if (k < 0) k = 0;
    if (k >= n) k = n - 1;

    // zero header + histogram (everything else is fully overwritten)
    (void)hipMemsetAsync(d_ws, 0, (WS_HIST + HIST_WORDS) * sizeof(unsigned int), stream);

    k_pass1<<<NBLK, 256, 0, stream>>>(x, n, ws, k);
    k_pass2<<<NBLK, 256, 0, stream>>>(x, out, n, ws);
}